// Round 1
// baseline (962.334 us; speedup 1.0000x reference)
//
#include <hip/hip_runtime.h>
#include <hip/hip_bf16.h>

typedef __bf16 bf16;
typedef __bf16 bf16x8 __attribute__((ext_vector_type(8)));
typedef float  f32x4  __attribute__((ext_vector_type(4)));
typedef float  f32x16 __attribute__((ext_vector_type(16)));

#define MFMA16(a,b,c) __builtin_amdgcn_mfma_f32_16x16x32_bf16(a,b,c,0,0,0)
#define MFMA32(a,b,c) __builtin_amdgcn_mfma_f32_32x32x16_bf16(a,b,c,0,0,0)

__device__ __forceinline__ f32x4 zero4() { f32x4 z; z[0]=0.f; z[1]=0.f; z[2]=0.f; z[3]=0.f; return z; }

// ---------------------------------------------------------------------------
// prep: transpose+convert weights f32 -> bf16 [n][k], materialize bias matrix
// ws layout (bytes):
//   0      : wqkvT  [384][128] bf16   (98304)
//   98304  : wprojT [128][128] bf16   (32768)
//   131072 : wfc1T  [512][128] bf16   (131072)
//   262144 : wfc2T  [128][512] bf16   (131072)
//   393216 : biasmat[8][64][64] f32   (131072)   total 524288 B
// ---------------------------------------------------------------------------
__global__ __launch_bounds__(512) void prep_kernel(
    const float* __restrict__ wqkv, const float* __restrict__ wproj,
    const float* __restrict__ wfc1, const float* __restrict__ wfc2,
    const float* __restrict__ btab, const int* __restrict__ relidx,
    bf16* __restrict__ wqkvT, bf16* __restrict__ wprojT,
    bf16* __restrict__ wfc1T, bf16* __restrict__ wfc2T,
    float* __restrict__ biasmat)
{
    int i = blockIdx.x * 512 + threadIdx.x;
    if (i < 49152) { int n = i >> 7, k = i & 127; wqkvT[i] = (bf16)wqkv[k*384 + n]; return; }
    i -= 49152;
    if (i < 16384) { int n = i >> 7, k = i & 127; wprojT[i] = (bf16)wproj[k*128 + n]; return; }
    i -= 16384;
    if (i < 65536) { int n = i >> 7, k = i & 127; wfc1T[i] = (bf16)wfc1[k*512 + n]; return; }
    i -= 65536;
    if (i < 65536) { int n = i >> 9, k = i & 511; wfc2T[i] = (bf16)wfc2[k*128 + n]; return; }
    i -= 65536;
    if (i < 32768) { int h = i >> 12, q = (i >> 6) & 63, kk = i & 63;
                     biasmat[i] = btab[relidx[q*64 + kk]*8 + h]; }
}

// LayerNorm: reads win f32 from Bs[0:32K) (swizzle (t&15)<<4), writes bf16 h to As
// ([tok][c] bf16, swizzle (t&7)<<4). 8 threads per token.
__device__ __forceinline__ void ln_to_A(const char* Bs, char* As,
                                        const float* __restrict__ g,
                                        const float* __restrict__ b, int tid)
{
    const int t = tid >> 3, p = tid & 7;
    const int swzW = (t & 15) << 4;
    float v[16];
    float s = 0.f, s2 = 0.f;
#pragma unroll
    for (int i = 0; i < 4; ++i) {
        f32x4 q = *(const f32x4*)(Bs + t*512 + ((p*64 + i*16) ^ swzW));
#pragma unroll
        for (int e = 0; e < 4; ++e) { float f = q[e]; v[i*4+e] = f; s += f; s2 += f*f; }
    }
#pragma unroll
    for (int m = 1; m < 8; m <<= 1) { s += __shfl_xor(s, m, 64); s2 += __shfl_xor(s2, m, 64); }
    const float mean = s * 0.0078125f;
    const float rs = rsqrtf(s2 * 0.0078125f - mean*mean + 1e-5f);
    const int swzH = (t & 7) << 4;
#pragma unroll
    for (int hlf = 0; hlf < 2; ++hlf) {
        bf16x8 hv;
#pragma unroll
        for (int e = 0; e < 8; ++e) {
            int c = p*16 + hlf*8 + e;
            hv[e] = (bf16)((v[hlf*8+e] - mean) * rs * g[c] + b[c]);
        }
        *(bf16x8*)(As + t*256 + ((p*32 + hlf*16) ^ swzH)) = hv;
    }
}

// ---------------------------------------------------------------------------
// fused Swin block: 1 window per block, 512 threads (8 waves = 8 heads)
// LDS: Bs = sm[0:49152)  (q/k/vT | P-bufs+win2 | g), As = sm[49152:65536) (h/o/h2)
// ---------------------------------------------------------------------------
__global__ __launch_bounds__(512) void swin_fused(
    const float* __restrict__ x,
    const float* __restrict__ ln1_g, const float* __restrict__ ln1_b,
    const float* __restrict__ b_qkv, const float* __restrict__ b_proj,
    const float* __restrict__ ln2_g, const float* __restrict__ ln2_b,
    const float* __restrict__ b_fc1, const float* __restrict__ b_fc2,
    const bf16* __restrict__ wqkvT, const bf16* __restrict__ wprojT,
    const bf16* __restrict__ wfc1T, const bf16* __restrict__ wfc2T,
    const float* __restrict__ biasmat,
    float* __restrict__ out)
{
    __shared__ __align__(16) char sm[65536];
    char* Bs = sm;
    char* As = sm + 49152;

    const int tid  = threadIdx.x;
    const int lane = tid & 63;
    const int wv   = tid >> 6;     // 0..7 == head
    const int l15  = lane & 15;
    const int l4   = lane >> 4;    // 0..3
    const int l31  = lane & 31;
    const int l5   = lane >> 5;    // 0..1

    // XCD-aware swizzle: consecutive wids land on the same XCD (4096 % 8 == 0)
    const int wid = ((blockIdx.x & 7) << 9) | (blockIdx.x >> 3);
    const int bb  = wid >> 10;
    const int hw  = (wid >> 5) & 31;
    const int wwi = wid & 31;

    const size_t base = (size_t)bb * 128 * 65536 + (size_t)(hw * 8) * 256 + (size_t)(wwi * 8);
    const float* xw  = x   + base;
    float*       outw = out + base;

    // ---------------- stage win (x window) f32 into Bs[0:32768) ----------------
#pragma unroll
    for (int it = 0; it < 16; ++it) {
        int idx = it*512 + tid;
        int c = idx >> 6, t = idx & 63;
        float v = xw[(size_t)c*65536 + (t>>3)*256 + (t&7)];
        *(float*)(Bs + t*512 + ((c*4) ^ ((t&15)<<4))) = v;
    }
    __syncthreads();

    // ---------------- LN1 -> h (bf16) in As ----------------
    ln_to_A(Bs, As, ln1_g, ln1_b, tid);
    __syncthreads();

    // ---------------- QKV GEMM: [64x128] @ [128x384] ----------------
    // wave wv owns n-tiles [wv*48, wv*48+48)
    {
        f32x4 acc[4][3];
#pragma unroll
        for (int mt = 0; mt < 4; ++mt)
#pragma unroll
            for (int nt = 0; nt < 3; ++nt) acc[mt][nt] = zero4();
        const int n0 = wv * 48;
#pragma unroll
        for (int ks = 0; ks < 4; ++ks) {
            bf16x8 bfr[3];
#pragma unroll
            for (int nt = 0; nt < 3; ++nt) {
                int n = n0 + nt*16 + l15;
                bfr[nt] = *(const bf16x8*)(wqkvT + n*128 + ks*32 + l4*8);
            }
#pragma unroll
            for (int mt = 0; mt < 4; ++mt) {
                int tok = mt*16 + l15;
                bf16x8 afr = *(const bf16x8*)(As + tok*256 + ((ks*64 + l4*16) ^ ((tok&7)<<4)));
#pragma unroll
                for (int nt = 0; nt < 3; ++nt)
                    acc[mt][nt] = MFMA16(afr, bfr[nt], acc[mt][nt]);
            }
        }
        // store q [tok][c], k [tok][c] (bf16, swz), v transposed sVt[d][tok]
#pragma unroll
        for (int nt = 0; nt < 3; ++nt) {
            const int nb = n0 + nt*16;
            const float bq = b_qkv[nb + l15];
#pragma unroll
            for (int mt = 0; mt < 4; ++mt) {
#pragma unroll
                for (int r = 0; r < 4; ++r) {
                    int tok = mt*16 + l4*4 + r;
                    bf16 hv = (bf16)(acc[mt][nt][r] + bq);
                    if (nb < 128) {
                        int c = nb + l15;
                        *(bf16*)(Bs + tok*256 + ((2*c) ^ ((tok&7)<<4))) = hv;
                    } else if (nb < 256) {
                        int c = nb - 128 + l15;
                        *(bf16*)(Bs + 16384 + tok*256 + ((2*c) ^ ((tok&7)<<4))) = hv;
                    } else {
                        int d = nb - 256 + l15;
                        *(bf16*)(Bs + 32768 + d*128 + ((2*tok) ^ ((d&7)<<4))) = hv;
                    }
                }
            }
        }
    }
    __syncthreads();

    // ---------------- QK^T per head (wave = head), 32x32x16 MFMA, K=16 ----------------
    f32x16 S[2][2];
    {
        bf16x8 qf[2], kf[2];
#pragma unroll
        for (int tm = 0; tm < 2; ++tm) {
            int tok = tm*32 + l31;
            qf[tm] = *(const bf16x8*)(Bs +         tok*256 + ((wv*32 + l5*16) ^ ((tok&7)<<4)));
            kf[tm] = *(const bf16x8*)(Bs + 16384 + tok*256 + ((wv*32 + l5*16) ^ ((tok&7)<<4)));
        }
        f32x16 z;
#pragma unroll
        for (int i = 0; i < 16; ++i) z[i] = 0.f;
        S[0][0] = MFMA32(qf[0], kf[0], z);
        S[0][1] = MFMA32(qf[0], kf[1], z);
        S[1][0] = MFMA32(qf[1], kf[0], z);
        S[1][1] = MFMA32(qf[1], kf[1], z);
    }
    __syncthreads();   // all QK reads done -> q,k region becomes P buffers

    // ---------------- softmax + PV, per tm half (32 rows) ----------------
    {
        const float SCALE = 0.35355339059327373f;   // HEADS^-0.5
        const float* bm = biasmat + wv * 4096;      // [64][64] for this head
        char* Pbuf = Bs + wv * 4096;                // [32][64] bf16 swizzled
#pragma unroll
        for (int tm = 0; tm < 2; ++tm) {
            // softmax rows (row = (r&3)+8*(r>>2)+4*l5), cols = l31 (+32)
#pragma unroll
            for (int r = 0; r < 16; ++r) {
                int row = (r&3) + 8*(r>>2) + 4*l5;
                float v0 = S[tm][0][r]*SCALE + bm[(tm*32+row)*64 + l31];
                float v1 = S[tm][1][r]*SCALE + bm[(tm*32+row)*64 + 32 + l31];
                float m = fmaxf(v0, v1);
#pragma unroll
                for (int sh = 1; sh < 32; sh <<= 1) m = fmaxf(m, __shfl_xor(m, sh, 64));
                float x0 = __expf(v0 - m), x1 = __expf(v1 - m);
                float s = x0 + x1;
#pragma unroll
                for (int sh = 1; sh < 32; sh <<= 1) s += __shfl_xor(s, sh, 64);
                float ri = 1.0f / s;
                char* pp = Pbuf + row*128;
                *(bf16*)(pp + ((2*l31)        ^ ((row&7)<<4))) = (bf16)(x0*ri);
                *(bf16*)(pp + ((2*(32+l31))   ^ ((row&7)<<4))) = (bf16)(x1*ri);
            }
            // PV: O[32x16] = P[32x64] @ V[64x16]
            f32x4 of[2]; of[0] = zero4(); of[1] = zero4();
#pragma unroll
            for (int ks = 0; ks < 2; ++ks) {
                int d = wv*16 + l15;
                bf16x8 vf = *(const bf16x8*)(Bs + 32768 + d*128 + ((ks*64 + l4*16) ^ ((d&7)<<4)));
#pragma unroll
                for (int mt = 0; mt < 2; ++mt) {
                    int rl = mt*16 + l15;
                    bf16x8 pf = *(const bf16x8*)(Pbuf + rl*128 + ((ks*64 + l4*16) ^ ((rl&7)<<4)));
                    of[mt] = MFMA16(pf, vf, of[mt]);
                }
            }
            // store O -> As [tok][c] bf16 swizzled
#pragma unroll
            for (int mt = 0; mt < 2; ++mt) {
#pragma unroll
                for (int r = 0; r < 4; ++r) {
                    int tok = tm*32 + mt*16 + l4*4 + r;
                    int c = wv*16 + l15;
                    *(bf16*)(As + tok*256 + ((2*c) ^ ((tok&7)<<4))) = (bf16)of[mt][r];
                }
            }
        }
    }
    __syncthreads();

    // ---------------- restage win f32 (residual) into Bs[0:32768) ----------------
#pragma unroll
    for (int it = 0; it < 16; ++it) {
        int idx = it*512 + tid;
        int c = idx >> 6, t = idx & 63;
        float v = xw[(size_t)c*65536 + (t>>3)*256 + (t&7)];
        *(float*)(Bs + t*512 + ((c*4) ^ ((t&15)<<4))) = v;
    }
    __syncthreads();

    // ---------------- proj GEMM + residual: win2 = win + O @ wproj + b ----------------
    {
        const int mt = wv >> 1;
        const int ncol0 = (wv & 1) * 64;
        f32x4 acc[4];
#pragma unroll
        for (int nt = 0; nt < 4; ++nt) acc[nt] = zero4();
#pragma unroll
        for (int ks = 0; ks < 4; ++ks) {
            int tok = mt*16 + l15;
            bf16x8 afr = *(const bf16x8*)(As + tok*256 + ((ks*64 + l4*16) ^ ((tok&7)<<4)));
#pragma unroll
            for (int nt = 0; nt < 4; ++nt) {
                int n = ncol0 + nt*16 + l15;
                bf16x8 bfr = *(const bf16x8*)(wprojT + n*128 + ks*32 + l4*8);
                acc[nt] = MFMA16(afr, bfr, acc[nt]);
            }
        }
#pragma unroll
        for (int nt = 0; nt < 4; ++nt) {
            int c = ncol0 + nt*16 + l15;
            float bp = b_proj[c];
#pragma unroll
            for (int r = 0; r < 4; ++r) {
                int tok = mt*16 + l4*4 + r;
                float* wp = (float*)(Bs + tok*512 + ((c*4) ^ ((tok&15)<<4)));
                *wp += acc[nt][r] + bp;
            }
        }
    }
    __syncthreads();

    // ---------------- LN2 -> h2 in As ----------------
    ln_to_A(Bs, As, ln2_g, ln2_b, tid);
    __syncthreads();

    // ---------------- MLP: fc1 (4 x 128-col chunks, exact GELU) + fc2 accum ----------------
    {
        const int mt = wv >> 1;
        const int ncol0 = (wv & 1) * 64;
        f32x4 acc2[4];
#pragma unroll
        for (int nt = 0; nt < 4; ++nt) acc2[nt] = zero4();
#pragma unroll
        for (int c4 = 0; c4 < 4; ++c4) {
            // fc1 chunk -> g (bf16, Bs+32768, [tok][cl] swizzled)
            {
                f32x4 a1[4];
#pragma unroll
                for (int nt = 0; nt < 4; ++nt) a1[nt] = zero4();
#pragma unroll
                for (int ks = 0; ks < 4; ++ks) {
                    int tok = mt*16 + l15;
                    bf16x8 afr = *(const bf16x8*)(As + tok*256 + ((ks*64 + l4*16) ^ ((tok&7)<<4)));
#pragma unroll
                    for (int nt = 0; nt < 4; ++nt) {
                        int n = c4*128 + ncol0 + nt*16 + l15;
                        bf16x8 bfr = *(const bf16x8*)(wfc1T + n*128 + ks*32 + l4*8);
                        a1[nt] = MFMA16(afr, bfr, a1[nt]);
                    }
                }
#pragma unroll
                for (int nt = 0; nt < 4; ++nt) {
                    int cl = ncol0 + nt*16 + l15;
                    float b1 = b_fc1[c4*128 + cl];
#pragma unroll
                    for (int r = 0; r < 4; ++r) {
                        int tok = mt*16 + l4*4 + r;
                        float u = a1[nt][r] + b1;
                        float gl = 0.5f * u * (1.0f + erff(u * 0.7071067811865475f));
                        *(bf16*)(Bs + 32768 + tok*256 + ((2*cl) ^ ((tok&7)<<4))) = (bf16)gl;
                    }
                }
            }
            __syncthreads();
            // fc2 partial: acc2 += g_chunk @ wfc2[chunk]
#pragma unroll
            for (int ks = 0; ks < 4; ++ks) {
                int tok = mt*16 + l15;
                bf16x8 afr = *(const bf16x8*)(Bs + 32768 + tok*256 + ((ks*64 + l4*16) ^ ((tok&7)<<4)));
#pragma unroll
                for (int nt = 0; nt < 4; ++nt) {
                    int n = ncol0 + nt*16 + l15;
                    bf16x8 bfr = *(const bf16x8*)(wfc2T + n*512 + c4*128 + ks*32 + l4*8);
                    acc2[nt] = MFMA16(afr, bfr, acc2[nt]);
                }
            }
            __syncthreads();
        }
        // final: win2 += acc2 + b_fc2
#pragma unroll
        for (int nt = 0; nt < 4; ++nt) {
            int c = ncol0 + nt*16 + l15;
            float bf_ = b_fc2[c];
#pragma unroll
            for (int r = 0; r < 4; ++r) {
                int tok = mt*16 + l4*4 + r;
                float* wp = (float*)(Bs + tok*512 + ((c*4) ^ ((tok&15)<<4)));
                *wp += acc2[nt][r] + bf_;
            }
        }
    }
    __syncthreads();

    // ---------------- write out (BCHW) ----------------
#pragma unroll
    for (int it = 0; it < 16; ++it) {
        int idx = it*512 + tid;
        int c = idx >> 6, t = idx & 63;
        outw[(size_t)c*65536 + (t>>3)*256 + (t&7)] =
            *(const float*)(Bs + t*512 + ((c*4) ^ ((t&15)<<4)));
    }
}

extern "C" void kernel_launch(void* const* d_in, const int* in_sizes, int n_in,
                              void* d_out, int out_size, void* d_ws, size_t ws_size,
                              hipStream_t stream) {
    const float* x      = (const float*)d_in[0];
    const float* ln1_g  = (const float*)d_in[1];
    const float* ln1_b  = (const float*)d_in[2];
    const float* w_qkv  = (const float*)d_in[3];
    const float* b_qkv  = (const float*)d_in[4];
    const float* w_proj = (const float*)d_in[5];
    const float* b_proj = (const float*)d_in[6];
    const float* btab   = (const float*)d_in[7];
    const float* ln2_g  = (const float*)d_in[8];
    const float* ln2_b  = (const float*)d_in[9];
    const float* w_fc1  = (const float*)d_in[10];
    const float* b_fc1  = (const float*)d_in[11];
    const float* w_fc2  = (const float*)d_in[12];
    const float* b_fc2  = (const float*)d_in[13];
    const int*   relix  = (const int*)d_in[14];
    float* out = (float*)d_out;

    char* ws = (char*)d_ws;                 // needs 524288 B
    bf16*  wqkvT   = (bf16*)(ws);
    bf16*  wprojT  = (bf16*)(ws + 98304);
    bf16*  wfc1T   = (bf16*)(ws + 131072);
    bf16*  wfc2T   = (bf16*)(ws + 262144);
    float* biasmat = (float*)(ws + 393216);

    prep_kernel<<<dim3(448), dim3(512), 0, stream>>>(
        w_qkv, w_proj, w_fc1, w_fc2, btab, relix,
        wqkvT, wprojT, wfc1T, wfc2T, biasmat);

    swin_fused<<<dim3(4096), dim3(512), 0, stream>>>(
        x, ln1_g, ln1_b, b_qkv, b_proj, ln2_g, ln2_b, b_fc1, b_fc2,
        wqkvT, wprojT, wfc1T, wfc2T, biasmat, out);
}

// Round 2
// 809.117 us; speedup vs baseline: 1.1894x; 1.1894x over previous
//
#include <hip/hip_runtime.h>
#include <hip/hip_bf16.h>
#include <stdint.h>

typedef __bf16 bf16;
typedef __bf16 bf16x8 __attribute__((ext_vector_type(8)));
typedef float  f32x4  __attribute__((ext_vector_type(4)));
typedef float  f32x16 __attribute__((ext_vector_type(16)));

#define MFMA16(a,b,c) __builtin_amdgcn_mfma_f32_16x16x32_bf16(a,b,c,0,0,0)
#define MFMA32(a,b,c) __builtin_amdgcn_mfma_f32_32x32x16_bf16(a,b,c,0,0,0)

__device__ __forceinline__ f32x4 zero4() { f32x4 z; z[0]=0.f; z[1]=0.f; z[2]=0.f; z[3]=0.f; return z; }
__device__ __forceinline__ f32x16 zero16() {
    f32x16 z;
#pragma unroll
    for (int i = 0; i < 16; ++i) z[i] = 0.f;
    return z;
}

__device__ __forceinline__ uint32_t packbf(float lo, float hi) {
    union { bf16 b[2]; uint32_t u; } t;
    t.b[0] = (bf16)lo; t.b[1] = (bf16)hi;
    return t.u;
}
__device__ __forceinline__ bf16x8 frag_from_words(uint32_t w0, uint32_t w1, uint32_t w2, uint32_t w3) {
    union { uint32_t u[4]; bf16x8 v; } t;
    t.u[0] = w0; t.u[1] = w1; t.u[2] = w2; t.u[3] = w3;
    return t.v;
}

// fast GELU (tanh form, max err ~3e-3 vs exact erf)
__device__ __forceinline__ float gelu_f(float u) {
    float u2 = u * u;
    float y  = u * (0.7978845608f + 0.0356774081f * u2);
    float e  = __expf(2.0f * y);
    float t  = 1.0f - 2.0f / (e + 1.0f);
    return 0.5f * u * (1.0f + t);
}

// ---------------------------------------------------------------------------
// prep: weights f32 -> bf16 [n][k]; bias matrix TRANSPOSED: bT[h][k][q]
// ws layout (bytes):
//   0      : wqkvT  [384][128] bf16   (98304)
//   98304  : wprojT [128][128] bf16   (32768)
//   131072 : wfc1T  [512][128] bf16   (131072)
//   262144 : wfc2T  [128][512] bf16   (131072)
//   393216 : bT     [8][64][64] f32   (131072)   total 524288 B
// ---------------------------------------------------------------------------
__global__ __launch_bounds__(512) void prep_kernel(
    const float* __restrict__ wqkv, const float* __restrict__ wproj,
    const float* __restrict__ wfc1, const float* __restrict__ wfc2,
    const float* __restrict__ btab, const int* __restrict__ relidx,
    bf16* __restrict__ wqkvT, bf16* __restrict__ wprojT,
    bf16* __restrict__ wfc1T, bf16* __restrict__ wfc2T,
    float* __restrict__ bT)
{
    int i = blockIdx.x * 512 + threadIdx.x;
    if (i < 49152) { int n = i >> 7, k = i & 127; wqkvT[i] = (bf16)wqkv[k*384 + n]; return; }
    i -= 49152;
    if (i < 16384) { int n = i >> 7, k = i & 127; wprojT[i] = (bf16)wproj[k*128 + n]; return; }
    i -= 16384;
    if (i < 65536) { int n = i >> 7, k = i & 127; wfc1T[i] = (bf16)wfc1[k*512 + n]; return; }
    i -= 65536;
    if (i < 65536) { int n = i >> 9, k = i & 511; wfc2T[i] = (bf16)wfc2[k*128 + n]; return; }
    i -= 65536;
    if (i < 32768) { int h = i >> 12, k = (i >> 6) & 63, q = i & 63;
                     bT[i] = btab[relidx[q*64 + k]*8 + h]; }
}

// LayerNorm: reads win f32 from sm[0:32K) (swizzle (t&15)<<4), writes bf16 h
// to dst ([tok][c] bf16, swizzle (tok&7)<<4). 8 threads per token.
__device__ __forceinline__ void ln_to_A(const char* Ws, char* dst,
                                        const float* __restrict__ g,
                                        const float* __restrict__ b, int tid)
{
    const int t = tid >> 3, p = tid & 7;
    const int swzW = (t & 15) << 4;
    float v[16];
    float s = 0.f, s2 = 0.f;
#pragma unroll
    for (int i = 0; i < 4; ++i) {
        f32x4 q = *(const f32x4*)(Ws + t*512 + ((p*64 + i*16) ^ swzW));
#pragma unroll
        for (int e = 0; e < 4; ++e) { float f = q[e]; v[i*4+e] = f; s += f; s2 += f*f; }
    }
#pragma unroll
    for (int m = 1; m < 8; m <<= 1) { s += __shfl_xor(s, m, 64); s2 += __shfl_xor(s2, m, 64); }
    const float mean = s * 0.0078125f;
    const float rs = rsqrtf(s2 * 0.0078125f - mean*mean + 1e-5f);
    const int swzH = (t & 7) << 4;
#pragma unroll
    for (int hlf = 0; hlf < 2; ++hlf) {
        bf16x8 hv;
#pragma unroll
        for (int e = 0; e < 8; ++e) {
            int c = p*16 + hlf*8 + e;
            hv[e] = (bf16)((v[hlf*8+e] - mean) * rs * g[c] + b[c]);
        }
        *(bf16x8*)(dst + t*256 + ((p*32 + hlf*16) ^ swzH)) = hv;
    }
}

// ---------------------------------------------------------------------------
// fused Swin block: 1 window per block, 512 threads (8 waves)
// LDS (64KB):
//  [0:32768)     : x-stage f32  ->  q[0:16K) + k[16K:32K)  ->  o[0:16K) + ln2scratch[16K:17K)
//                  -> MLP g ping-pong (g0 [0:16K), g1 [16K:32K)) -> out-stage f32
//  [32768:49152) : h bf16 [tok][c]  ->  h2 bf16
//  [49152:65536) : vT bf16 [head][d 16][tok 64]
// ---------------------------------------------------------------------------
__global__ __launch_bounds__(512, 4) void swin_fused(
    const float* __restrict__ x,
    const float* __restrict__ ln1_g, const float* __restrict__ ln1_b,
    const float* __restrict__ b_qkv, const float* __restrict__ b_proj,
    const float* __restrict__ ln2_g, const float* __restrict__ ln2_b,
    const float* __restrict__ b_fc1, const float* __restrict__ b_fc2,
    const bf16* __restrict__ wqkvT, const bf16* __restrict__ wprojT,
    const bf16* __restrict__ wfc1T, const bf16* __restrict__ wfc2T,
    const float* __restrict__ bT,
    float* __restrict__ out)
{
    __shared__ __align__(16) char sm[65536];

    const int tid  = threadIdx.x;
    const int lane = tid & 63;
    const int wv   = tid >> 6;
    const int l15  = lane & 15;
    const int l4   = (lane >> 4) & 3;
    const int l31  = lane & 31;
    const int hi   = lane >> 5;          // 0/1
    const int fmt  = wv >> 1;            // proj/MLP row-tile
    const int fn0  = (wv & 1) * 64;      // proj/MLP col base

    // XCD-aware swizzle (4096 % 8 == 0)
    const int wid = ((blockIdx.x & 7) << 9) | (blockIdx.x >> 3);
    const int bb  = wid >> 10;
    const int hw  = (wid >> 5) & 31;
    const int wwi = wid & 31;
    const size_t base = (size_t)bb * 128 * 65536 + (size_t)(hw * 8) * 256 + (size_t)(wwi * 8);
    const float* xw   = x   + base;
    float*       outw = out + base;

    // ---------------- phase 1: stage x window f32 ----------------
#pragma unroll
    for (int it = 0; it < 16; ++it) {
        int idx = it*512 + tid;
        int c = idx >> 6, t = idx & 63;
        float v = xw[(size_t)c*65536 + (t>>3)*256 + (t&7)];
        *(float*)(sm + t*512 + ((c*4) ^ ((t&15)<<4))) = v;
    }
    __syncthreads();

    // ---------------- phase 2: LN1 -> h; win residual -> regs ----------------
    ln_to_A(sm, sm + 32768, ln1_g, ln1_b, tid);
    float win[4][4];
#pragma unroll
    for (int nt = 0; nt < 4; ++nt)
#pragma unroll
        for (int r = 0; r < 4; ++r) {
            int tok = fmt*16 + l4*4 + r;
            int c   = fn0 + nt*16 + l15;
            win[nt][r] = *(const float*)(sm + tok*512 + ((c*4) ^ ((tok&15)<<4)));
        }
    __syncthreads();

    // ---------------- phase 3: QKV GEMM ----------------
    // wave wv: q/k cols [wv*32, wv*32+32); v cols [256+wv*16, 256+wv*16+16)
    {
        f32x4 aq[4][2], av[4];
#pragma unroll
        for (int mt = 0; mt < 4; ++mt) { aq[mt][0] = zero4(); aq[mt][1] = zero4(); av[mt] = zero4(); }
        const int nq0 = wv * 32;
        const int nv  = 256 + wv*16 + l15;
#pragma unroll
        for (int ks = 0; ks < 4; ++ks) {
            bf16x8 bq0 = *(const bf16x8*)(wqkvT + (nq0      + l15)*128 + ks*32 + l4*8);
            bf16x8 bq1 = *(const bf16x8*)(wqkvT + (nq0 + 16 + l15)*128 + ks*32 + l4*8);
            bf16x8 bv  = *(const bf16x8*)(wqkvT + nv*128 + ks*32 + l4*8);
#pragma unroll
            for (int mt = 0; mt < 4; ++mt) {
                int tok = mt*16 + l15;
                bf16x8 afr = *(const bf16x8*)(sm + 32768 + tok*256 + ((ks*64 + l4*16) ^ ((tok&7)<<4)));
                aq[mt][0] = MFMA16(afr, bq0, aq[mt][0]);
                aq[mt][1] = MFMA16(afr, bq1, aq[mt][1]);
                av[mt]    = MFMA16(afr, bv,  av[mt]);
            }
        }
        // store q [0:16K) / k [16K:32K) as [tok][c] bf16 swizzled
#pragma unroll
        for (int nt = 0; nt < 2; ++nt) {
            int n = nq0 + nt*16 + l15;
            float bb_ = b_qkv[n];
            char* rb = (n < 128) ? sm : (sm + 16384);
            int c = n & 127;
#pragma unroll
            for (int mt = 0; mt < 4; ++mt)
#pragma unroll
                for (int r = 0; r < 4; ++r) {
                    int tok = mt*16 + l4*4 + r;
                    *(bf16*)(rb + tok*256 + ((2*c) ^ ((tok&7)<<4))) = (bf16)(aq[mt][nt][r] + bb_);
                }
        }
        // store vT [head][d][tok] packed pairs
        {
            float bb_ = b_qkv[nv];
            int d = l15;
            char* vb = sm + 49152 + wv*2048 + d*128;
            int sz = (d & 7) << 4;
#pragma unroll
            for (int mt = 0; mt < 4; ++mt) {
                int t0 = mt*16 + l4*4;
                *(uint32_t*)(vb + ((2*t0)     ^ sz)) = packbf(av[mt][0]+bb_, av[mt][1]+bb_);
                *(uint32_t*)(vb + ((2*t0 + 4) ^ sz)) = packbf(av[mt][2]+bb_, av[mt][3]+bb_);
            }
        }
    }
    __syncthreads();

    // ---------------- phase 4: attention (wave = head), swapped QK^T ----------------
    f32x16 Ot[2];
    Ot[0] = zero16(); Ot[1] = zero16();
    {
        const float SCALE = 0.35355339059327373f;
        bf16x8 kf[2];
#pragma unroll
        for (int tk = 0; tk < 2; ++tk) {
            int tok = tk*32 + l31;
            kf[tk] = *(const bf16x8*)(sm + 16384 + tok*256 + ((wv*32 + hi*16) ^ ((tok&7)<<4)));
        }
#pragma unroll
        for (int tq = 0; tq < 2; ++tq) {
            int q = tq*32 + l31;
            bf16x8 qf = *(const bf16x8*)(sm + q*256 + ((wv*32 + hi*16) ^ ((q&7)<<4)));
            f32x16 s0 = MFMA32(kf[0], qf, zero16());   // S^T rows k in [0,32)
            f32x16 s1 = MFMA32(kf[1], qf, zero16());   // S^T rows k in [32,64)
            const float* bh = bT + wv*4096 + q;        // + k*64
            float vmax = -3.0e38f;
#pragma unroll
            for (int r = 0; r < 16; ++r) {
                int k0 = (r&3) + 8*((r>>2)&3) + 4*hi;
                s0[r] = s0[r]*SCALE + bh[k0*64];
                s1[r] = s1[r]*SCALE + bh[(k0+32)*64];
                vmax = fmaxf(vmax, fmaxf(s0[r], s1[r]));
            }
            vmax = fmaxf(vmax, __shfl_xor(vmax, 32, 64));
            float ss = 0.f;
#pragma unroll
            for (int r = 0; r < 16; ++r) {
                s0[r] = __expf(s0[r] - vmax);
                s1[r] = __expf(s1[r] - vmax);
                ss += s0[r] + s1[r];
            }
            ss += __shfl_xor(ss, 32, 64);
            float ri = 1.0f / ss;
#pragma unroll
            for (int r = 0; r < 16; ++r) { s0[r] *= ri; s1[r] *= ri; }
            // PV: O^T[d][q] += V^T[d][k] * P^T[k][q], 4 K-steps of 16
#pragma unroll
            for (int ks = 0; ks < 4; ++ks) {
                uint32_t own[4];
#pragma unroll
                for (int i = 0; i < 4; ++i) {
                    const int j = 2*(i&1) + 4*((2*ks + (i>>1)) & 3) + 16*(ks>>1);
                    if (j < 16) own[i] = packbf(s0[j], s0[j+1]);
                    else        own[i] = packbf(s1[j-16], s1[j-15]);
                }
                uint32_t sw0 = __shfl_xor(own[0], 32, 64);
                uint32_t sw1 = __shfl_xor(own[1], 32, 64);
                uint32_t sw2 = __shfl_xor(own[2], 32, 64);
                uint32_t sw3 = __shfl_xor(own[3], 32, 64);
                uint32_t w0 = hi ? sw2    : own[0];
                uint32_t w1 = hi ? sw3    : own[1];
                uint32_t w2 = hi ? own[2] : sw0;
                uint32_t w3 = hi ? own[3] : sw1;
                bf16x8 pf = frag_from_words(w0, w1, w2, w3);
                int dd = l31 & 15;
                bf16x8 vf = *(const bf16x8*)(sm + 49152 + wv*2048 + dd*128
                                             + ((ks*32 + hi*16) ^ ((dd&7)<<4)));
                Ot[tq] = MFMA32(vf, pf, Ot[tq]);
            }
        }
    }
    __syncthreads();
    // write o [q][c] bf16 swizzled into [0:16K)
#pragma unroll
    for (int tq = 0; tq < 2; ++tq) {
        int q = tq*32 + l31;
#pragma unroll
        for (int r = 0; r < 8; r += 2) {
            int d = (r&3) + 8*(r>>2) + 4*hi;
            *(uint32_t*)(sm + q*256 + ((2*(wv*16 + d)) ^ ((q&7)<<4))) = packbf(Ot[tq][r], Ot[tq][r+1]);
        }
    }
    __syncthreads();

    // ---------------- phase 5: proj + residual (in regs) ----------------
    float win2[4][4];
    {
        f32x4 acc[4];
#pragma unroll
        for (int nt = 0; nt < 4; ++nt) acc[nt] = zero4();
#pragma unroll
        for (int ks = 0; ks < 4; ++ks) {
            int tok = fmt*16 + l15;
            bf16x8 afr = *(const bf16x8*)(sm + tok*256 + ((ks*64 + l4*16) ^ ((tok&7)<<4)));
#pragma unroll
            for (int nt = 0; nt < 4; ++nt) {
                int n = fn0 + nt*16 + l15;
                bf16x8 bfr = *(const bf16x8*)(wprojT + n*128 + ks*32 + l4*8);
                acc[nt] = MFMA16(afr, bfr, acc[nt]);
            }
        }
#pragma unroll
        for (int nt = 0; nt < 4; ++nt) {
            float bp = b_proj[fn0 + nt*16 + l15];
#pragma unroll
            for (int r = 0; r < 4; ++r) win2[nt][r] = win[nt][r] + acc[nt][r] + bp;
        }
    }

    // ---------------- phase 6: LN2 from regs ----------------
    float mean[4], rstd[4];
    {
        float s[4], s2[4];
#pragma unroll
        for (int r = 0; r < 4; ++r) {
            s[r]  = win2[0][r] + win2[1][r] + win2[2][r] + win2[3][r];
            s2[r] = win2[0][r]*win2[0][r] + win2[1][r]*win2[1][r]
                  + win2[2][r]*win2[2][r] + win2[3][r]*win2[3][r];
#pragma unroll
            for (int m = 1; m < 16; m <<= 1) {
                s[r]  += __shfl_xor(s[r],  m, 64);
                s2[r] += __shfl_xor(s2[r], m, 64);
            }
        }
        float2* scr = (float2*)(sm + 16384);
        if (l15 == 0) {
#pragma unroll
            for (int r = 0; r < 4; ++r) {
                int tok = fmt*16 + l4*4 + r;
                scr[tok*2 + (wv&1)] = make_float2(s[r], s2[r]);
            }
        }
        __syncthreads();
#pragma unroll
        for (int r = 0; r < 4; ++r) {
            int tok = fmt*16 + l4*4 + r;
            float2 p = scr[tok*2 + ((wv&1)^1)];
            float tot = s[r] + p.x, tot2 = s2[r] + p.y;
            float m = tot * 0.0078125f;
            mean[r] = m;
            rstd[r] = rsqrtf(tot2*0.0078125f - m*m + 1e-5f);
        }
    }
    // h2 -> [32768:49152)
#pragma unroll
    for (int nt = 0; nt < 4; ++nt) {
        int c = fn0 + nt*16 + l15;
        float gg = ln2_g[c], bb2 = ln2_b[c];
#pragma unroll
        for (int r = 0; r < 4; ++r) {
            int tok = fmt*16 + l4*4 + r;
            *(bf16*)(sm + 32768 + tok*256 + ((2*c) ^ ((tok&7)<<4)))
                = (bf16)((win2[nt][r] - mean[r]) * rstd[r] * gg + bb2);
        }
    }
    __syncthreads();

    // ---------------- phase 7: MLP (g ping-pong, fast GELU) ----------------
    f32x4 acc2[4];
#pragma unroll
    for (int nt = 0; nt < 4; ++nt) acc2[nt] = zero4();
#pragma unroll
    for (int c4 = 0; c4 < 4; ++c4) {
        char* gbuf = sm + (c4 & 1) * 16384;
        {
            f32x4 a1[4];
#pragma unroll
            for (int nt = 0; nt < 4; ++nt) a1[nt] = zero4();
#pragma unroll
            for (int ks = 0; ks < 4; ++ks) {
                int tok = fmt*16 + l15;
                bf16x8 afr = *(const bf16x8*)(sm + 32768 + tok*256 + ((ks*64 + l4*16) ^ ((tok&7)<<4)));
#pragma unroll
                for (int nt = 0; nt < 4; ++nt) {
                    int n = c4*128 + fn0 + nt*16 + l15;
                    bf16x8 bfr = *(const bf16x8*)(wfc1T + n*128 + ks*32 + l4*8);
                    a1[nt] = MFMA16(afr, bfr, a1[nt]);
                }
            }
#pragma unroll
            for (int nt = 0; nt < 4; ++nt) {
                int cl = fn0 + nt*16 + l15;
                float b1 = b_fc1[c4*128 + cl];
#pragma unroll
                for (int r = 0; r < 4; ++r) {
                    int tok = fmt*16 + l4*4 + r;
                    float u = a1[nt][r] + b1;
                    *(bf16*)(gbuf + tok*256 + ((2*cl) ^ ((tok&7)<<4))) = (bf16)gelu_f(u);
                }
            }
        }
        __syncthreads();
#pragma unroll
        for (int ks = 0; ks < 4; ++ks) {
            int tok = fmt*16 + l15;
            bf16x8 afr = *(const bf16x8*)(gbuf + tok*256 + ((ks*64 + l4*16) ^ ((tok&7)<<4)));
#pragma unroll
            for (int nt = 0; nt < 4; ++nt) {
                int n = fn0 + nt*16 + l15;
                bf16x8 bfr = *(const bf16x8*)(wfc2T + n*512 + c4*128 + ks*32 + l4*8);
                acc2[nt] = MFMA16(afr, bfr, acc2[nt]);
            }
        }
    }
    // final residual in regs
#pragma unroll
    for (int nt = 0; nt < 4; ++nt) {
        float bf_ = b_fc2[fn0 + nt*16 + l15];
#pragma unroll
        for (int r = 0; r < 4; ++r) win2[nt][r] += acc2[nt][r] + bf_;
    }
    __syncthreads();   // drain last g reads before overwriting [0:32K)

    // ---------------- phase 8: out staging + coalesced BCHW write ----------------
#pragma unroll
    for (int nt = 0; nt < 4; ++nt)
#pragma unroll
        for (int r = 0; r < 4; ++r) {
            int tok = fmt*16 + l4*4 + r;
            int c   = fn0 + nt*16 + l15;
            *(float*)(sm + tok*512 + ((c*4) ^ ((tok&15)<<4))) = win2[nt][r];
        }
    __syncthreads();
#pragma unroll
    for (int it = 0; it < 16; ++it) {
        int idx = it*512 + tid;
        int c = idx >> 6, t = idx & 63;
        outw[(size_t)c*65536 + (t>>3)*256 + (t&7)] =
            *(const float*)(sm + t*512 + ((c*4) ^ ((t&15)<<4)));
    }
}

extern "C" void kernel_launch(void* const* d_in, const int* in_sizes, int n_in,
                              void* d_out, int out_size, void* d_ws, size_t ws_size,
                              hipStream_t stream) {
    const float* x      = (const float*)d_in[0];
    const float* ln1_g  = (const float*)d_in[1];
    const float* ln1_b  = (const float*)d_in[2];
    const float* w_qkv  = (const float*)d_in[3];
    const float* b_qkv  = (const float*)d_in[4];
    const float* w_proj = (const float*)d_in[5];
    const float* b_proj = (const float*)d_in[6];
    const float* btab   = (const float*)d_in[7];
    const float* ln2_g  = (const float*)d_in[8];
    const float* ln2_b  = (const float*)d_in[9];
    const float* w_fc1  = (const float*)d_in[10];
    const float* b_fc1  = (const float*)d_in[11];
    const float* w_fc2  = (const float*)d_in[12];
    const float* b_fc2  = (const float*)d_in[13];
    const int*   relix  = (const int*)d_in[14];
    float* out = (float*)d_out;

    char* ws = (char*)d_ws;                 // needs 524288 B
    bf16*  wqkvT  = (bf16*)(ws);
    bf16*  wprojT = (bf16*)(ws + 98304);
    bf16*  wfc1T  = (bf16*)(ws + 131072);
    bf16*  wfc2T  = (bf16*)(ws + 262144);
    float* bT     = (float*)(ws + 393216);

    prep_kernel<<<dim3(448), dim3(512), 0, stream>>>(
        w_qkv, w_proj, w_fc1, w_fc2, btab, relix,
        wqkvT, wprojT, wfc1T, wfc2T, bT);

    swin_fused<<<dim3(4096), dim3(512), 0, stream>>>(
        x, ln1_g, ln1_b, b_qkv, b_proj, ln2_g, ln2_b, b_fc1, b_fc2,
        wqkvT, wprojT, wfc1T, wfc2T, bT, out);
}